// Round 1
// baseline (1324.370 us; speedup 1.0000x reference)
//
#include <hip/hip_runtime.h>

// SLAYER SNN forward, 6 layers, T=2048.
// All heavy math in double ("true value" policy) because outputs are binary
// spikes that must match the golden fp32 reference exactly.
//
// Refractory scan identity: REF_TAIL contribution r[t] = C*e2[t] with
//   e1[t+1] = a*(e1[t]+s[t]), e2[t+1] = a*(e2[t]+e1[t]+s[t]), a=e^-1, C=-2e
// and C*a == -2 exactly, so u[t+1] = p[t+1] - 2*((e1+e2)+s).
// Truncation (K_REF=32) tail ~4e-13 -- far below fp32 noise, ignored.

#define T_BINS 2048
#define K_SRM  100
#define AEXP   0.36787944117144233   // e^-1
#define PF     32                    // scan prefetch depth

// ---------------- init: SRM kernel + prefix-sum tables (double) -------------
__global__ __launch_bounds__(256) void k_init(double* __restrict__ Scum,
                                              double* __restrict__ srm) {
  int tid = threadIdx.x;
  for (int k = tid; k < K_SRM; k += 256) {
    double tk = (double)k;
    srm[k] = (tk * 0.1) * exp(1.0 - tk * 0.1);
  }
  __syncthreads();
  if (tid == 0) {
    double acc = 0.0;
    for (int t = 0; t < K_SRM; ++t) { acc += srm[t]; Scum[t] = acc; }
  }
  __syncthreads();
  double total = Scum[K_SRM - 1];
  for (int t = K_SRM + tid; t <= T_BINS; t += 256) Scum[t] = total;
}

// ---------------- conv1: [3,32,32] x [6,3,5,5] -> c1[4704] ------------------
__global__ __launch_bounds__(256) void k_conv1(const float* __restrict__ x,
                                               const float* __restrict__ W,
                                               float* __restrict__ c1) {
  int idx = blockIdx.x * blockDim.x + threadIdx.x;
  if (idx >= 4704) return;
  int o = idx / 784, r = idx % 784, i = r / 28, j = r % 28;
  double acc = 0.0;
  for (int ci = 0; ci < 3; ++ci)
    for (int ky = 0; ky < 5; ++ky) {
      const float* xr = x + ci * 1024 + (i + ky) * 32 + j;
      const float* wr = W + ((o * 3 + ci) * 5 + ky) * 5;
#pragma unroll
      for (int kx = 0; kx < 5; ++kx)
        acc += (double)xr[kx] * (double)wr[kx];
    }
  c1[idx] = (float)acc;
}

// ---------------- layer1 spike scan: p1[t] = c1*Scum[t] ---------------------
// 4704 threads, byte spike output [t][4704]. Constant-p fast path for t>=99.
__global__ __launch_bounds__(256) void k_scan1(const float* __restrict__ c1,
                                               const double* __restrict__ Scum_g,
                                               unsigned char* __restrict__ s1b) {
  __shared__ double Sc[K_SRM];
  for (int k = threadIdx.x; k < K_SRM; k += blockDim.x) Sc[k] = Scum_g[k];
  __syncthreads();
  int n = blockIdx.x * blockDim.x + threadIdx.x;
  if (n >= 4704) return;
  double w = (double)c1[n];
  double e1 = 0.0, e2 = 0.0;
  double u = 0.0;                       // w*Scum[0] == 0
  unsigned char* outp = s1b + n;
  int t = 0;
#pragma unroll 4
  for (; t < K_SRM - 1; ++t) {          // ramp phase, uses Sc[t+1]
    double s = (u >= 1.0) ? 1.0 : 0.0;
    outp[(size_t)t * 4704] = (unsigned char)s;
    u = w * Sc[t + 1] - 2.0 * ((e1 + e2) + s);
    double t1 = e1 + s;
    e2 = AEXP * (e2 + t1);
    e1 = AEXP * t1;
  }
  double wS = w * Sc[K_SRM - 1];        // steady-state drive
#pragma unroll 8
  for (; t < T_BINS; ++t) {
    double s = (u >= 1.0) ? 1.0 : 0.0;
    outp[(size_t)t * 4704] = (unsigned char)s;
    u = wS - 2.0 * ((e1 + e2) + s);
    double t1 = e1 + s;
    e2 = AEXP * (e2 + t1);
    e1 = AEXP * t1;
  }
}

// ---------------- pool: 2x2 sum * 1.1 -> y2[t][1176] ------------------------
__global__ __launch_bounds__(256) void k_pool(const unsigned char* __restrict__ s1b,
                                              float* __restrict__ y2) {
  int idx = blockIdx.x * blockDim.x + threadIdx.x;
  if (idx >= 1176 * T_BINS) return;
  int t = idx / 1176, n2 = idx - t * 1176;
  int c = n2 / 196, r = n2 % 196, i = r / 14, j = r % 14;
  const unsigned char* b = s1b + (size_t)t * 4704 + c * 784 + (2 * i) * 28 + 2 * j;
  int cnt = (int)b[0] + (int)b[1] + (int)b[28] + (int)b[29];
  // n*1.1f rounds identically to the reference's conv-tree of 1.1f terms
  y2[idx] = (float)cnt * 1.1f;
}

// ---------------- causal FIR along t (100 taps, double acc) -----------------
__global__ __launch_bounds__(256) void k_fir(const float* __restrict__ z,
                                             float* __restrict__ p,
                                             const double* __restrict__ srm_g,
                                             int N) {
  __shared__ double srm[K_SRM];
  for (int k = threadIdx.x; k < K_SRM; k += blockDim.x) srm[k] = srm_g[k];
  __syncthreads();
  int idx = blockIdx.x * blockDim.x + threadIdx.x;
  if (idx >= N * T_BINS) return;
  int t = idx / N, n = idx - t * N;
  int kmax = t < (K_SRM - 1) ? t : (K_SRM - 1);
  const float* zp = z + n;
  double acc = 0.0;
  for (int k = 1; k <= kmax; ++k)       // tap 0 is exactly zero
    acc += srm[k] * (double)zp[(size_t)(t - k) * N];
  p[idx] = (float)acc;
}

// ---------------- generic spike scan with 32-deep register prefetch ---------
// p layout [t][N]; output at sout[t*strideT + n*strideN].
// Speculative read of p row T_BINS is in-bounds by workspace construction.
__global__ __launch_bounds__(256) void k_scan(const float* __restrict__ p,
                                              float* __restrict__ sout,
                                              int N, long strideT, long strideN) {
  int n = blockIdx.x * blockDim.x + threadIdx.x;
  if (n >= N) return;
  const float* pn = p + n;
  double e1 = 0.0, e2 = 0.0;
  double u = (double)pn[0];
  float bufA[PF], bufB[PF];
  size_t out_addr = (size_t)n * (size_t)strideN;
#define PREF(BUF, TBASE_)                                            \
  { int tb_ = (TBASE_);                                              \
    _Pragma("unroll")                                                \
    for (int j_ = 0; j_ < PF; ++j_) {                                \
      int row_ = tb_ + j_;                                           \
      row_ = row_ > T_BINS ? T_BINS : row_;                          \
      BUF[j_] = pn[(size_t)row_ * (size_t)N];                        \
    } }
#define GRP(BUF)                                                     \
  { _Pragma("unroll")                                                \
    for (int j_ = 0; j_ < PF; ++j_) {                                \
      double s = (u >= 1.0) ? 1.0 : 0.0;                             \
      sout[out_addr] = (float)s;                                     \
      out_addr += (size_t)strideT;                                   \
      u = (double)BUF[j_] - 2.0 * ((e1 + e2) + s);                   \
      double t1 = e1 + s;                                            \
      e2 = AEXP * (e2 + t1);                                         \
      e1 = AEXP * t1;                                                \
    } }
  PREF(bufA, 1)
  for (int g = 0; g < T_BINS / PF; g += 2) {
    PREF(bufB, (g + 1) * PF + 1)
    GRP(bufA)
    PREF(bufA, (g + 2) * PF + 1)
    GRP(bufB)
  }
#undef PREF
#undef GRP
}

// ---------------- conv2: per-t [6,14,14] x [16,6,5,5] -> z3[t][1600] --------
__global__ __launch_bounds__(256) void k_conv2(const float* __restrict__ s2,
                                               const float* __restrict__ W,
                                               float* __restrict__ z3) {
  __shared__ float ls[1176];
  __shared__ float lw[2400];
  int t = blockIdx.x;
  for (int i = threadIdx.x; i < 1176; i += 256) ls[i] = s2[(size_t)t * 1176 + i];
  for (int i = threadIdx.x; i < 2400; i += 256) lw[i] = W[i];
  __syncthreads();
  for (int rr = threadIdx.x; rr < 1600; rr += 256) {
    int o = rr / 100, ij = rr % 100, i = ij / 10, j = ij % 10;
    double acc = 0.0;
    for (int ci = 0; ci < 6; ++ci)
      for (int ky = 0; ky < 5; ++ky) {
        int sb = ci * 196 + (i + ky) * 14 + j;
        int wb = ((o * 6 + ci) * 5 + ky) * 5;
#pragma unroll
        for (int kx = 0; kx < 5; ++kx)
          acc += (double)ls[sb + kx] * (double)lw[wb + kx];
      }
    z3[(size_t)t * 1600 + rr] = (float)acc;
  }
}

// ---------------- dense with TB time-rows per block (W reuse) ---------------
template <int TB>
__global__ __launch_bounds__(256) void k_dense_tb(const float* __restrict__ sin,
                                                  const float* __restrict__ W,
                                                  float* __restrict__ zout,
                                                  int Nin, int Nout) {
  extern __shared__ float rows[];       // TB*Nin floats
  int t0 = blockIdx.x * TB;
  for (int i = threadIdx.x; i < TB * Nin; i += 256)
    rows[i] = sin[(size_t)t0 * Nin + i];
  __syncthreads();
  for (int o = threadIdx.x; o < Nout; o += 256) {
    const float* w = W + (size_t)o * Nin;
    double acc[TB];
#pragma unroll
    for (int q = 0; q < TB; ++q) acc[q] = 0.0;
    for (int c = 0; c < Nin; ++c) {
      double wv = (double)w[c];
#pragma unroll
      for (int q = 0; q < TB; ++q)
        acc[q] += wv * (double)rows[q * Nin + c];
    }
#pragma unroll
    for (int q = 0; q < TB; ++q)
      zout[(size_t)(t0 + q) * Nout + o] = (float)acc[q];
  }
}

// ---------------- dense3: tiny (10x150 per t) -------------------------------
__global__ __launch_bounds__(256) void k_dense3(const float* __restrict__ sin,
                                                const float* __restrict__ W,
                                                float* __restrict__ z) {
  int idx = blockIdx.x * blockDim.x + threadIdx.x;
  if (idx >= T_BINS * 10) return;
  int t = idx / 10, o = idx - t * 10;
  const float* w = W + o * 150;
  const float* s = sin + (size_t)t * 150;
  double acc = 0.0;
  for (int c = 0; c < 150; ++c)
    acc += (double)w[c] * (double)s[c];
  z[idx] = (float)acc;
}

// ---------------- launch ----------------------------------------------------
extern "C" void kernel_launch(void* const* d_in, const int* in_sizes, int n_in,
                              void* d_out, int out_size, void* d_ws, size_t ws_size,
                              hipStream_t stream) {
  const float* x   = (const float*)d_in[0];
  const float* Wc1 = (const float*)d_in[1];
  const float* Wc2 = (const float*)d_in[2];
  const float* Wf1 = (const float*)d_in[3];
  const float* Wf2 = (const float*)d_in[4];
  const float* Wf3 = (const float*)d_in[5];
  float* out = (float*)d_out;
  char* ws = (char*)d_ws;

  // Workspace layout (~49.3 MB, with overlays; each scan's speculative
  // p[row 2048] read lands in the next live buffer -- read-only, unused).
  double* Scum = (double*)(ws + 0);            // double[2049]
  double* srm  = (double*)(ws + 16400);        // double[100]
  float*  c1   = (float*)(ws + 17216);         // float[4704]
  const size_t A0 = 65536, SZB = 9633792;      // SZB = 1176*2048*4 = 4704*2048
  unsigned char* s1b = (unsigned char*)(ws + A0);        // [t][4704] bytes
  float* y2 = (float*)(ws + A0 + SZB);                   // [t][1176]
  float* p2 = (float*)(ws + A0 + 2 * SZB);
  float* s2 = (float*)(ws + A0 + 3 * SZB);
  float* p3 = (float*)(ws + A0);                         // overlays s1b+y2 (dead)
  float* s3 = (float*)(ws + A0 + 13107200);              // overlays p2 (dead)
  const size_t B0 = A0 + 4 * SZB;
  float* z3 = (float*)(ws + B0);                         // [t][1600]
  float* z4 = (float*)(ws + B0);                         // overlays z3 (dead)
  float* p4 = (float*)(ws + B0 + 2457600);
  float* s4 = (float*)(ws + B0 + 4915200);
  float* z5 = (float*)(ws + B0 + 7372800);
  float* p5 = (float*)(ws + B0 + 8601600);
  float* s5 = (float*)(ws + B0 + 9830400);
  float* z6 = (float*)(ws + B0 + 11059200);
  float* p6 = (float*)(ws + B0 + 11141120);

  k_init<<<1, 256, 0, stream>>>(Scum, srm);
  k_conv1<<<19, 256, 0, stream>>>(x, Wc1, c1);
  k_scan1<<<19, 256, 0, stream>>>(c1, Scum, s1b);
  k_pool<<<(1176 * T_BINS) / 256, 256, 0, stream>>>(s1b, y2);
  k_fir<<<(1176 * T_BINS) / 256, 256, 0, stream>>>(y2, p2, srm, 1176);
  k_scan<<<5, 256, 0, stream>>>(p2, s2, 1176, 1176L, 1L);
  k_conv2<<<T_BINS, 256, 0, stream>>>(s2, Wc2, z3);
  k_fir<<<(1600 * T_BINS) / 256, 256, 0, stream>>>(z3, p3, srm, 1600);
  k_scan<<<7, 256, 0, stream>>>(p3, s3, 1600, 1600L, 1L);
  k_dense_tb<8><<<T_BINS / 8, 256, 8 * 1600 * 4, stream>>>(s3, Wf1, z4, 1600, 300);
  k_fir<<<(300 * T_BINS) / 256, 256, 0, stream>>>(z4, p4, srm, 300);
  k_scan<<<2, 256, 0, stream>>>(p4, s4, 300, 300L, 1L);
  k_dense_tb<8><<<T_BINS / 8, 256, 8 * 300 * 4, stream>>>(s4, Wf2, z5, 300, 150);
  k_fir<<<(150 * T_BINS) / 256, 256, 0, stream>>>(z5, p5, srm, 150);
  k_scan<<<1, 256, 0, stream>>>(p5, s5, 150, 150L, 1L);
  k_dense3<<<(T_BINS * 10) / 256, 256, 0, stream>>>(s5, Wf3, z6);
  k_fir<<<(10 * T_BINS) / 256, 256, 0, stream>>>(z6, p6, srm, 10);
  k_scan<<<1, 64, 0, stream>>>(p6, out, 10, 1L, 2048L);

  (void)in_sizes; (void)n_in; (void)out_size; (void)ws_size;
}

// Round 2
// 913.817 us; speedup vs baseline: 1.4493x; 1.4493x over previous
//
#include <hip/hip_runtime.h>

// SLAYER SNN forward, 6 layers, T=2048.
// Heavy math in double ("true value" policy) because outputs are binary
// spikes that must match the golden fp32 reference exactly.
//
// Refractory scan identity: REF_TAIL contribution r[t] = C*e2[t] with
//   e1[t+1] = a*(e1[t]+s[t]), e2[t+1] = a*(e2[t]+e1[t]+s[t]), a=e^-1, C=-2e
// and C*a == -2 exactly, so u[t+1] = p[t+1] - 2*((e1+e2)+s).
// Truncation (K_REF=32) tail ~4e-13 -- far below fp32 noise, ignored.
//
// Dense layers: inputs are binary spikes; adding w*0==0.0 to a double acc is
// an exact no-op, so skipping inactive c (order-preserving compaction) gives
// a BITWISE-identical sum. W is pre-transposed so the per-c row read is
// coalesced across output lanes.

#define T_BINS 2048
#define K_SRM  100
#define AEXP   0.36787944117144233   // e^-1
#define PF     32                    // scan prefetch depth

// ---------------- init: SRM kernel + prefix-sum tables (double) -------------
__global__ __launch_bounds__(256) void k_init(double* __restrict__ Scum,
                                              double* __restrict__ srm) {
  int tid = threadIdx.x;
  for (int k = tid; k < K_SRM; k += 256) {
    double tk = (double)k;
    srm[k] = (tk * 0.1) * exp(1.0 - tk * 0.1);
  }
  __syncthreads();
  if (tid == 0) {
    double acc = 0.0;
    for (int t = 0; t < K_SRM; ++t) { acc += srm[t]; Scum[t] = acc; }
  }
  __syncthreads();
  double total = Scum[K_SRM - 1];
  for (int t = K_SRM + tid; t <= T_BINS; t += 256) Scum[t] = total;
}

// ---------------- conv1: [3,32,32] x [6,3,5,5] -> c1[4704] ------------------
__global__ __launch_bounds__(256) void k_conv1(const float* __restrict__ x,
                                               const float* __restrict__ W,
                                               float* __restrict__ c1) {
  int idx = blockIdx.x * blockDim.x + threadIdx.x;
  if (idx >= 4704) return;
  int o = idx / 784, r = idx % 784, i = r / 28, j = r % 28;
  double acc = 0.0;
  for (int ci = 0; ci < 3; ++ci)
    for (int ky = 0; ky < 5; ++ky) {
      const float* xr = x + ci * 1024 + (i + ky) * 32 + j;
      const float* wr = W + ((o * 3 + ci) * 5 + ky) * 5;
#pragma unroll
      for (int kx = 0; kx < 5; ++kx)
        acc += (double)xr[kx] * (double)wr[kx];
    }
  c1[idx] = (float)acc;
}

// ---------------- layer1 spike scan: p1[t] = c1*Scum[t] ---------------------
__global__ __launch_bounds__(256) void k_scan1(const float* __restrict__ c1,
                                               const double* __restrict__ Scum_g,
                                               unsigned char* __restrict__ s1b) {
  __shared__ double Sc[K_SRM];
  for (int k = threadIdx.x; k < K_SRM; k += blockDim.x) Sc[k] = Scum_g[k];
  __syncthreads();
  int n = blockIdx.x * blockDim.x + threadIdx.x;
  if (n >= 4704) return;
  double w = (double)c1[n];
  double e1 = 0.0, e2 = 0.0;
  double u = 0.0;                       // w*Scum[0] == 0
  unsigned char* outp = s1b + n;
  int t = 0;
#pragma unroll 4
  for (; t < K_SRM - 1; ++t) {          // ramp phase, uses Sc[t+1]
    double s = (u >= 1.0) ? 1.0 : 0.0;
    outp[(size_t)t * 4704] = (unsigned char)s;
    u = w * Sc[t + 1] - 2.0 * ((e1 + e2) + s);
    double t1 = e1 + s;
    e2 = AEXP * (e2 + t1);
    e1 = AEXP * t1;
  }
  double wS = w * Sc[K_SRM - 1];        // steady-state drive
#pragma unroll 8
  for (; t < T_BINS; ++t) {
    double s = (u >= 1.0) ? 1.0 : 0.0;
    outp[(size_t)t * 4704] = (unsigned char)s;
    u = wS - 2.0 * ((e1 + e2) + s);
    double t1 = e1 + s;
    e2 = AEXP * (e2 + t1);
    e1 = AEXP * t1;
  }
}

// ---------------- pool: 2x2 sum * 1.1 -> y2[t][1176] ------------------------
__global__ __launch_bounds__(256) void k_pool(const unsigned char* __restrict__ s1b,
                                              float* __restrict__ y2) {
  int idx = blockIdx.x * blockDim.x + threadIdx.x;
  if (idx >= 1176 * T_BINS) return;
  int t = idx / 1176, n2 = idx - t * 1176;
  int c = n2 / 196, r = n2 % 196, i = r / 14, j = r % 14;
  const unsigned char* b = s1b + (size_t)t * 4704 + c * 784 + (2 * i) * 28 + 2 * j;
  int cnt = (int)b[0] + (int)b[1] + (int)b[28] + (int)b[29];
  y2[idx] = (float)cnt * 1.1f;
}

// ---------------- causal FIR along t (100 taps, double acc) -----------------
__global__ __launch_bounds__(256) void k_fir(const float* __restrict__ z,
                                             float* __restrict__ p,
                                             const double* __restrict__ srm_g,
                                             int N) {
  __shared__ double srm[K_SRM];
  for (int k = threadIdx.x; k < K_SRM; k += blockDim.x) srm[k] = srm_g[k];
  __syncthreads();
  int idx = blockIdx.x * blockDim.x + threadIdx.x;
  if (idx >= N * T_BINS) return;
  int t = idx / N, n = idx - t * N;
  int kmax = t < (K_SRM - 1) ? t : (K_SRM - 1);
  const float* zp = z + n;
  double acc = 0.0;
  for (int k = 1; k <= kmax; ++k)       // tap 0 is exactly zero
    acc += srm[k] * (double)zp[(size_t)(t - k) * N];
  p[idx] = (float)acc;
}

// ---------------- generic spike scan with 32-deep register prefetch ---------
__global__ __launch_bounds__(256) void k_scan(const float* __restrict__ p,
                                              float* __restrict__ sout,
                                              int N, long strideT, long strideN) {
  int n = blockIdx.x * blockDim.x + threadIdx.x;
  if (n >= N) return;
  const float* pn = p + n;
  double e1 = 0.0, e2 = 0.0;
  double u = (double)pn[0];
  float bufA[PF], bufB[PF];
  size_t out_addr = (size_t)n * (size_t)strideN;
#define PREF(BUF, TBASE_)                                            \
  { int tb_ = (TBASE_);                                              \
    _Pragma("unroll")                                                \
    for (int j_ = 0; j_ < PF; ++j_) {                                \
      int row_ = tb_ + j_;                                           \
      row_ = row_ > T_BINS ? T_BINS : row_;                          \
      BUF[j_] = pn[(size_t)row_ * (size_t)N];                        \
    } }
#define GRP(BUF)                                                     \
  { _Pragma("unroll")                                                \
    for (int j_ = 0; j_ < PF; ++j_) {                                \
      double s = (u >= 1.0) ? 1.0 : 0.0;                             \
      sout[out_addr] = (float)s;                                     \
      out_addr += (size_t)strideT;                                   \
      u = (double)BUF[j_] - 2.0 * ((e1 + e2) + s);                   \
      double t1 = e1 + s;                                            \
      e2 = AEXP * (e2 + t1);                                         \
      e1 = AEXP * t1;                                                \
    } }
  PREF(bufA, 1)
  for (int g = 0; g < T_BINS / PF; g += 2) {
    PREF(bufB, (g + 1) * PF + 1)
    GRP(bufA)
    PREF(bufA, (g + 2) * PF + 1)
    GRP(bufB)
  }
#undef PREF
#undef GRP
}

// ---------------- conv2: per-t [6,14,14] x [16,6,5,5] -> z3[t][1600] --------
__global__ __launch_bounds__(256) void k_conv2(const float* __restrict__ s2,
                                               const float* __restrict__ W,
                                               float* __restrict__ z3) {
  __shared__ float ls[1176];
  __shared__ float lw[2400];
  int t = blockIdx.x;
  for (int i = threadIdx.x; i < 1176; i += 256) ls[i] = s2[(size_t)t * 1176 + i];
  for (int i = threadIdx.x; i < 2400; i += 256) lw[i] = W[i];
  __syncthreads();
  for (int rr = threadIdx.x; rr < 1600; rr += 256) {
    int o = rr / 100, ij = rr % 100, i = ij / 10, j = ij % 10;
    double acc = 0.0;
    for (int ci = 0; ci < 6; ++ci)
      for (int ky = 0; ky < 5; ++ky) {
        int sb = ci * 196 + (i + ky) * 14 + j;
        int wb = ((o * 6 + ci) * 5 + ky) * 5;
#pragma unroll
        for (int kx = 0; kx < 5; ++kx)
          acc += (double)ls[sb + kx] * (double)lw[wb + kx];
      }
    z3[(size_t)t * 1600 + rr] = (float)acc;
  }
}

// ---------------- weight transpose: WT[c][o] = W[o][c] ----------------------
__global__ __launch_bounds__(256) void k_transpose(const float* __restrict__ W,
                                                   float* __restrict__ WT,
                                                   int Nout, int Nin) {
  int idx = blockIdx.x * blockDim.x + threadIdx.x;
  if (idx >= Nout * Nin) return;
  int c = idx / Nout, o = idx - c * Nout;   // write-coalesced
  WT[idx] = W[o * Nin + c];
}

// ---------------- sparse dense: z[t][o] = sum_{c active} WT[c][o] -----------
// One block per t. Order-preserving compaction of active c (ascending), then
// double accumulation over the active list -> bitwise equal to the dense sum.
__global__ __launch_bounds__(256) void k_dense_sparse(const float* __restrict__ s,
                                                      const float* __restrict__ WT,
                                                      float* __restrict__ z,
                                                      int Nin, int Nout) {
  __shared__ int list[1600];
  __shared__ int wsum[4];
  int t = blockIdx.x;
  const float* srow = s + (size_t)t * Nin;
  int tid = threadIdx.x, lane = tid & 63, wv = tid >> 6;
  int base = 0;
  for (int cb = 0; cb < Nin; cb += 256) {
    int c = cb + tid;
    bool a = (c < Nin) && (srow[c] != 0.0f);
    unsigned long long m = __ballot(a);
    if (lane == 0) wsum[wv] = __popcll(m);
    __syncthreads();
    int off = base;
    for (int i = 0; i < wv; ++i) off += wsum[i];
    if (a) list[off + __popcll(m & ((1ULL << lane) - 1))] = c;
    base += wsum[0] + wsum[1] + wsum[2] + wsum[3];
    __syncthreads();
  }
  int nact = base;
  for (int o = tid; o < Nout; o += 256) {
    double acc = 0.0;
    for (int k = 0; k < nact; ++k)
      acc += (double)WT[(size_t)list[k] * Nout + o];
    z[(size_t)t * Nout + o] = (float)acc;
  }
}

// ---------------- launch ----------------------------------------------------
extern "C" void kernel_launch(void* const* d_in, const int* in_sizes, int n_in,
                              void* d_out, int out_size, void* d_ws, size_t ws_size,
                              hipStream_t stream) {
  const float* x   = (const float*)d_in[0];
  const float* Wc1 = (const float*)d_in[1];
  const float* Wc2 = (const float*)d_in[2];
  const float* Wf1 = (const float*)d_in[3];
  const float* Wf2 = (const float*)d_in[4];
  const float* Wf3 = (const float*)d_in[5];
  float* out = (float*)d_out;
  char* ws = (char*)d_ws;

  // Workspace layout (~47.5 MB, with overlays; each scan's speculative
  // p[row 2048] read lands in the next live buffer -- read-only, unused).
  double* Scum = (double*)(ws + 0);            // double[2049]
  double* srm  = (double*)(ws + 16400);        // double[100]
  float*  c1   = (float*)(ws + 17216);         // float[4704]
  const size_t A0 = 65536, SZB = 9633792;      // SZB = 1176*2048*4 = 4704*2048
  unsigned char* s1b = (unsigned char*)(ws + A0);        // [t][4704] bytes
  float* y2 = (float*)(ws + A0 + SZB);                   // [t][1176]
  float* p2 = (float*)(ws + A0 + 2 * SZB);
  float* s2 = (float*)(ws + A0 + 3 * SZB);
  float* p3 = (float*)(ws + A0);                         // overlays s1b+y2 (dead)
  float* s3 = (float*)(ws + A0 + 13107200);              // overlays p2 (dead)
  // After scan3, p3 region [A0, A0+13107200) is dead -> WT overlays it.
  float* WT1 = (float*)(ws + A0);                        // 1600x300 = 1.92MB
  float* WT2 = (float*)(ws + A0 + 1920000);              // 300x150
  float* WT3 = (float*)(ws + A0 + 1920000 + 180000);     // 150x10
  const size_t B0 = A0 + 4 * SZB;
  float* z3 = (float*)(ws + B0);                         // [t][1600]
  float* z4 = (float*)(ws + B0);                         // overlays z3 (dead)
  float* p4 = (float*)(ws + B0 + 2457600);
  float* s4 = (float*)(ws + B0 + 4915200);
  float* z5 = (float*)(ws + B0 + 7372800);
  float* p5 = (float*)(ws + B0 + 8601600);
  float* s5 = (float*)(ws + B0 + 9830400);
  float* z6 = (float*)(ws + B0 + 11059200);
  float* p6 = (float*)(ws + B0 + 11141120);

  k_init<<<1, 256, 0, stream>>>(Scum, srm);
  k_conv1<<<19, 256, 0, stream>>>(x, Wc1, c1);
  k_scan1<<<19, 256, 0, stream>>>(c1, Scum, s1b);
  k_pool<<<(1176 * T_BINS) / 256, 256, 0, stream>>>(s1b, y2);
  k_fir<<<(1176 * T_BINS) / 256, 256, 0, stream>>>(y2, p2, srm, 1176);
  k_scan<<<5, 256, 0, stream>>>(p2, s2, 1176, 1176L, 1L);
  k_conv2<<<T_BINS, 256, 0, stream>>>(s2, Wc2, z3);
  k_fir<<<(1600 * T_BINS) / 256, 256, 0, stream>>>(z3, p3, srm, 1600);
  k_scan<<<7, 256, 0, stream>>>(p3, s3, 1600, 1600L, 1L);
  // p3 now dead -> stage transposed weights in its region
  k_transpose<<<(1600 * 300 + 255) / 256, 256, 0, stream>>>(Wf1, WT1, 300, 1600);
  k_transpose<<<(300 * 150 + 255) / 256, 256, 0, stream>>>(Wf2, WT2, 150, 300);
  k_transpose<<<(150 * 10 + 255) / 256, 256, 0, stream>>>(Wf3, WT3, 10, 150);
  k_dense_sparse<<<T_BINS, 256, 0, stream>>>(s3, WT1, z4, 1600, 300);
  k_fir<<<(300 * T_BINS) / 256, 256, 0, stream>>>(z4, p4, srm, 300);
  k_scan<<<2, 256, 0, stream>>>(p4, s4, 300, 300L, 1L);
  k_dense_sparse<<<T_BINS, 256, 0, stream>>>(s4, WT2, z5, 300, 150);
  k_fir<<<(150 * T_BINS) / 256, 256, 0, stream>>>(z5, p5, srm, 150);
  k_scan<<<1, 256, 0, stream>>>(p5, s5, 150, 150L, 1L);
  k_dense_sparse<<<T_BINS, 256, 0, stream>>>(s5, WT3, z6, 150, 10);
  k_fir<<<(10 * T_BINS) / 256, 256, 0, stream>>>(z6, p6, srm, 10);
  k_scan<<<1, 64, 0, stream>>>(p6, out, 10, 1L, 2048L);

  (void)in_sizes; (void)n_in; (void)out_size; (void)ws_size;
}

// Round 3
// 864.870 us; speedup vs baseline: 1.5313x; 1.0566x over previous
//
#include <hip/hip_runtime.h>

// SLAYER SNN forward, 6 layers, T=2048.
// Heavy math in double ("true value" policy): outputs are binary spikes that
// must match the golden fp32 reference exactly; double noise (~1e-13) is far
// below the reference's own fp32 noise (~1e-5), so any double summation ORDER
// is safe -- we exploit this for multi-accumulator ILP.
//
// Refractory scan identity: REF_TAIL contribution r[t] = C*e2[t] with
//   e1[t+1] = a*(e1[t]+s[t]), e2[t+1] = a*(e2[t]+e1[t]+s[t]), a=e^-1, C=-2e
// and C*a == -2 exactly, so u[t+1] = p[t+1] - 2*((e1+e2)+s).
// Truncation (K_REF=32) tail ~4e-13 -- below fp32 noise, ignored.
//
// Spike tensors are stored as BYTES (0/1), pooled counts as BYTES (0..4):
// consumers reconstruct the exact fp32 values ((float)cnt*1.1f etc.).

#define T_BINS 2048
#define K_SRM  100
#define AEXP   0.36787944117144233   // e^-1
#define PF     32                    // scan prefetch depth

// ---------------- init: SRM kernel + prefix-sum tables (double) -------------
__global__ __launch_bounds__(256) void k_init(double* __restrict__ Scum,
                                              double* __restrict__ srm) {
  int tid = threadIdx.x;
  for (int k = tid; k < K_SRM; k += 256) {
    double tk = (double)k;
    srm[k] = (tk * 0.1) * exp(1.0 - tk * 0.1);
  }
  __syncthreads();
  if (tid == 0) {
    double acc = 0.0;
    for (int t = 0; t < K_SRM; ++t) { acc += srm[t]; Scum[t] = acc; }
  }
  __syncthreads();
  double total = Scum[K_SRM - 1];
  for (int t = K_SRM + tid; t <= T_BINS; t += 256) Scum[t] = total;
}

// ---------------- conv1: [3,32,32] x [6,3,5,5] -> c1[4704] ------------------
__global__ __launch_bounds__(256) void k_conv1(const float* __restrict__ x,
                                               const float* __restrict__ W,
                                               float* __restrict__ c1) {
  int idx = blockIdx.x * blockDim.x + threadIdx.x;
  if (idx >= 4704) return;
  int o = idx / 784, r = idx % 784, i = r / 28, j = r % 28;
  double acc = 0.0;
  for (int ci = 0; ci < 3; ++ci)
    for (int ky = 0; ky < 5; ++ky) {
      const float* xr = x + ci * 1024 + (i + ky) * 32 + j;
      const float* wr = W + ((o * 3 + ci) * 5 + ky) * 5;
#pragma unroll
      for (int kx = 0; kx < 5; ++kx)
        acc += (double)xr[kx] * (double)wr[kx];
    }
  c1[idx] = (float)acc;
}

// ---------------- layer1 spike scan: p1[t] = c1*Scum[t] (exact truncated) ---
__global__ __launch_bounds__(256) void k_scan1(const float* __restrict__ c1,
                                               const double* __restrict__ Scum_g,
                                               unsigned char* __restrict__ s1b) {
  __shared__ double Sc[K_SRM];
  for (int k = threadIdx.x; k < K_SRM; k += blockDim.x) Sc[k] = Scum_g[k];
  __syncthreads();
  int n = blockIdx.x * blockDim.x + threadIdx.x;
  if (n >= 4704) return;
  double w = (double)c1[n];
  double e1 = 0.0, e2 = 0.0;
  double u = 0.0;                       // w*Scum[0] == 0
  unsigned char* outp = s1b + n;
  int t = 0;
#pragma unroll 4
  for (; t < K_SRM - 1; ++t) {          // ramp phase, uses Sc[t+1]
    double s = (u >= 1.0) ? 1.0 : 0.0;
    outp[(size_t)t * 4704] = (unsigned char)s;
    u = w * Sc[t + 1] - 2.0 * ((e1 + e2) + s);
    double t1 = e1 + s;
    e2 = AEXP * (e2 + t1);
    e1 = AEXP * t1;
  }
  double wS = w * Sc[K_SRM - 1];        // steady-state drive
#pragma unroll 8
  for (; t < T_BINS; ++t) {
    double s = (u >= 1.0) ? 1.0 : 0.0;
    outp[(size_t)t * 4704] = (unsigned char)s;
    u = wS - 2.0 * ((e1 + e2) + s);
    double t1 = e1 + s;
    e2 = AEXP * (e2 + t1);
    e1 = AEXP * t1;
  }
}

// ---------------- pool: 2x2 spike count -> y2b[t][1176] bytes ---------------
__global__ __launch_bounds__(256) void k_pool(const unsigned char* __restrict__ s1b,
                                              unsigned char* __restrict__ y2b) {
  int idx = blockIdx.x * blockDim.x + threadIdx.x;
  if (idx >= 1176 * T_BINS) return;
  int t = idx / 1176, n2 = idx - t * 1176;
  int c = n2 / 196, r = n2 % 196, i = r / 14, j = r % 14;
  const unsigned char* b = s1b + (size_t)t * 4704 + c * 784 + (2 * i) * 28 + 2 * j;
  y2b[idx] = (unsigned char)((int)b[0] + (int)b[1] + (int)b[28] + (int)b[29]);
}

// ---------------- causal FIR along t (100 taps, 4-acc double) ---------------
template <typename Tin, bool PSCALE>
__global__ __launch_bounds__(256) void k_fir(const Tin* __restrict__ z,
                                             float* __restrict__ p,
                                             const double* __restrict__ srm_g,
                                             int N) {
  __shared__ double srm[K_SRM];
  for (int k = threadIdx.x; k < K_SRM; k += blockDim.x) srm[k] = srm_g[k];
  __syncthreads();
  int idx = blockIdx.x * blockDim.x + threadIdx.x;
  if (idx >= N * T_BINS) return;
  int t = idx / N, n = idx - t * N;
  int kmax = t < (K_SRM - 1) ? t : (K_SRM - 1);
  const Tin* zp = z + n;
#define CVT_(v) (PSCALE ? (double)((float)(v) * 1.1f) : (double)(v))
  double a0 = 0.0, a1 = 0.0, a2 = 0.0, a3 = 0.0;
  int k = 1;                            // tap 0 is exactly zero
  for (; k + 3 <= kmax; k += 4) {
    a0 += srm[k]     * CVT_(zp[(size_t)(t - k)     * N]);
    a1 += srm[k + 1] * CVT_(zp[(size_t)(t - k - 1) * N]);
    a2 += srm[k + 2] * CVT_(zp[(size_t)(t - k - 2) * N]);
    a3 += srm[k + 3] * CVT_(zp[(size_t)(t - k - 3) * N]);
  }
  for (; k <= kmax; ++k)
    a0 += srm[k] * CVT_(zp[(size_t)(t - k) * N]);
#undef CVT_
  p[idx] = (float)((a0 + a1) + (a2 + a3));
}

// ---------------- generic spike scan with 32-deep register prefetch ---------
template <typename Tout>
__global__ __launch_bounds__(256) void k_scan(const float* __restrict__ p,
                                              Tout* __restrict__ sout,
                                              int N, long strideT, long strideN) {
  int n = blockIdx.x * blockDim.x + threadIdx.x;
  if (n >= N) return;
  const float* pn = p + n;
  double e1 = 0.0, e2 = 0.0;
  double u = (double)pn[0];
  float bufA[PF], bufB[PF];
  size_t out_addr = (size_t)n * (size_t)strideN;
#define PREF(BUF, TBASE_)                                            \
  { int tb_ = (TBASE_);                                              \
    _Pragma("unroll")                                                \
    for (int j_ = 0; j_ < PF; ++j_) {                                \
      int row_ = tb_ + j_;                                           \
      row_ = row_ > T_BINS ? T_BINS : row_;                          \
      BUF[j_] = pn[(size_t)row_ * (size_t)N];                        \
    } }
#define GRP(BUF)                                                     \
  { _Pragma("unroll")                                                \
    for (int j_ = 0; j_ < PF; ++j_) {                                \
      double s = (u >= 1.0) ? 1.0 : 0.0;                             \
      sout[out_addr] = (Tout)s;                                      \
      out_addr += (size_t)strideT;                                   \
      u = (double)BUF[j_] - 2.0 * ((e1 + e2) + s);                   \
      double t1 = e1 + s;                                            \
      e2 = AEXP * (e2 + t1);                                         \
      e1 = AEXP * t1;                                                \
    } }
  PREF(bufA, 1)
  for (int g = 0; g < T_BINS / PF; g += 2) {
    PREF(bufB, (g + 1) * PF + 1)
    GRP(bufA)
    PREF(bufA, (g + 2) * PF + 1)
    GRP(bufB)
  }
#undef PREF
#undef GRP
}

// ---------------- conv2: per-t [6,14,14] x [16,6,5,5] -> z3[t][1600] --------
__global__ __launch_bounds__(256) void k_conv2(const unsigned char* __restrict__ s2b,
                                               const float* __restrict__ W,
                                               float* __restrict__ z3) {
  __shared__ float ls[1176];
  __shared__ float lw[2400];
  int t = blockIdx.x;
  for (int i = threadIdx.x; i < 1176; i += 256)
    ls[i] = (float)s2b[(size_t)t * 1176 + i];
  for (int i = threadIdx.x; i < 2400; i += 256) lw[i] = W[i];
  __syncthreads();
  for (int rr = threadIdx.x; rr < 1600; rr += 256) {
    int o = rr / 100, ij = rr % 100, i = ij / 10, j = ij % 10;
    double acc = 0.0;
    for (int ci = 0; ci < 6; ++ci)
      for (int ky = 0; ky < 5; ++ky) {
        int sb = ci * 196 + (i + ky) * 14 + j;
        int wb = ((o * 6 + ci) * 5 + ky) * 5;
#pragma unroll
        for (int kx = 0; kx < 5; ++kx)
          acc += (double)ls[sb + kx] * (double)lw[wb + kx];
      }
    z3[(size_t)t * 1600 + rr] = (float)acc;
  }
}

// ---------------- weight transpose: WT[c][o] = W[o][c] ----------------------
__global__ __launch_bounds__(256) void k_transpose(const float* __restrict__ W,
                                                   float* __restrict__ WT,
                                                   int Nout, int Nin) {
  int idx = blockIdx.x * blockDim.x + threadIdx.x;
  if (idx >= Nout * Nin) return;
  int c = idx / Nout, o = idx - c * Nout;   // write-coalesced
  WT[idx] = W[o * Nin + c];
}

// ---------------- sparse dense: z[t][o] = sum_{c active} WT[c][o] -----------
// One block per t. Order-preserving compaction of active c (ascending), then
// 8-accumulator double sum over the active list (8 loads in flight).
template <int NCH>
__global__ __launch_bounds__(256) void k_dense_sparse(const unsigned char* __restrict__ s,
                                                      const float* __restrict__ WT,
                                                      float* __restrict__ z,
                                                      int Nin, int Nout) {
  __shared__ int list[1600];
  __shared__ int wcnt[NCH][4];
  int t = blockIdx.x;
  const unsigned char* srow = s + (size_t)t * Nin;
  int tid = threadIdx.x, lane = tid & 63, wv = tid >> 6;
  unsigned long long msave[NCH];
  bool asave[NCH];
#pragma unroll
  for (int ci = 0; ci < NCH; ++ci) {
    int c = ci * 256 + tid;
    bool a = (c < Nin) && (srow[c] != 0);
    unsigned long long m = __ballot(a);
    msave[ci] = m; asave[ci] = a;
    if (lane == 0) wcnt[ci][wv] = __popcll(m);
  }
  __syncthreads();
  int nact = 0;
#pragma unroll
  for (int ci = 0; ci < NCH; ++ci) {
    int off = nact;
    for (int w = 0; w < wv; ++w) off += wcnt[ci][w];
    if (asave[ci]) {
      int c = ci * 256 + tid;
      list[off + __popcll(msave[ci] & ((1ULL << lane) - 1))] = c;
    }
    nact += wcnt[ci][0] + wcnt[ci][1] + wcnt[ci][2] + wcnt[ci][3];
  }
  __syncthreads();
  for (int o = tid; o < Nout; o += 256) {
    const float* col = WT + o;
    double a0 = 0, a1 = 0, a2 = 0, a3 = 0, a4 = 0, a5 = 0, a6 = 0, a7 = 0;
    int k = 0;
    for (; k + 8 <= nact; k += 8) {
      a0 += (double)col[(size_t)list[k + 0] * Nout];
      a1 += (double)col[(size_t)list[k + 1] * Nout];
      a2 += (double)col[(size_t)list[k + 2] * Nout];
      a3 += (double)col[(size_t)list[k + 3] * Nout];
      a4 += (double)col[(size_t)list[k + 4] * Nout];
      a5 += (double)col[(size_t)list[k + 5] * Nout];
      a6 += (double)col[(size_t)list[k + 6] * Nout];
      a7 += (double)col[(size_t)list[k + 7] * Nout];
    }
    for (; k < nact; ++k) a0 += (double)col[(size_t)list[k] * Nout];
    z[(size_t)t * Nout + o] =
        (float)(((a0 + a1) + (a2 + a3)) + ((a4 + a5) + (a6 + a7)));
  }
}

// ---------------- launch ----------------------------------------------------
extern "C" void kernel_launch(void* const* d_in, const int* in_sizes, int n_in,
                              void* d_out, int out_size, void* d_ws, size_t ws_size,
                              hipStream_t stream) {
  const float* x   = (const float*)d_in[0];
  const float* Wc1 = (const float*)d_in[1];
  const float* Wc2 = (const float*)d_in[2];
  const float* Wf1 = (const float*)d_in[3];
  const float* Wf2 = (const float*)d_in[4];
  const float* Wf3 = (const float*)d_in[5];
  float* out = (float*)d_out;
  char* ws = (char*)d_ws;

  // Workspace (~44.7 MB). Single Z and P arenas reused by consecutive layers
  // (lifetimes strictly serial); +8KB pad on each arena absorbs the scans'
  // speculative row-2048 prefetch reads.
  double* Scum = (double*)(ws + 0);              // double[2049]
  double* srm  = (double*)(ws + 16640);          // double[100]
  float*  c1   = (float*)(ws + 17536);           // float[4704]
  const size_t ZA = 65536;                       // Z arena: 13,115,392 B
  const size_t PA = ZA + 13115392;               // P arena: 13,115,392 B
  const size_t SA = PA + 13115392;               // s1b: 9,641,984
  const size_t SB = SA + 9641984;                // s2b: 2,416,640
  const size_t SC = SB + 2416640;                // s3b: 3,284,992
  const size_t SD = SC + 3284992;                // s4b:   622,592
  const size_t SE = SD + 622592;                 // s5b:   315,392
  const size_t WA = SE + 315392;                 // WT1: 1,928,192
  const size_t WB = WA + 1928192;                // WT2:   188,416
  const size_t WC = WB + 188416;                 // WT3:    14,336
  unsigned char* y2b = (unsigned char*)(ws + ZA);  // pooled counts (pre-conv2)
  float* zA = (float*)(ws + ZA);                   // z3/z4/z5/z6
  float* pA = (float*)(ws + PA);                   // p2..p6
  unsigned char* s1b = (unsigned char*)(ws + SA);
  unsigned char* s2b = (unsigned char*)(ws + SB);
  unsigned char* s3b = (unsigned char*)(ws + SC);
  unsigned char* s4b = (unsigned char*)(ws + SD);
  unsigned char* s5b = (unsigned char*)(ws + SE);
  float* WT1 = (float*)(ws + WA);
  float* WT2 = (float*)(ws + WB);
  float* WT3 = (float*)(ws + WC);

  k_init<<<1, 256, 0, stream>>>(Scum, srm);
  k_conv1<<<19, 256, 0, stream>>>(x, Wc1, c1);
  k_transpose<<<(1600 * 300 + 255) / 256, 256, 0, stream>>>(Wf1, WT1, 300, 1600);
  k_transpose<<<(300 * 150 + 255) / 256, 256, 0, stream>>>(Wf2, WT2, 150, 300);
  k_transpose<<<(150 * 10 + 255) / 256, 256, 0, stream>>>(Wf3, WT3, 10, 150);
  k_scan1<<<19, 256, 0, stream>>>(c1, Scum, s1b);
  k_pool<<<(1176 * T_BINS) / 256, 256, 0, stream>>>(s1b, y2b);
  k_fir<unsigned char, true><<<(1176 * T_BINS) / 256, 256, 0, stream>>>(y2b, pA, srm, 1176);
  k_scan<unsigned char><<<5, 256, 0, stream>>>(pA, s2b, 1176, 1176L, 1L);
  k_conv2<<<T_BINS, 256, 0, stream>>>(s2b, Wc2, zA);
  k_fir<float, false><<<(1600 * T_BINS) / 256, 256, 0, stream>>>(zA, pA, srm, 1600);
  k_scan<unsigned char><<<7, 256, 0, stream>>>(pA, s3b, 1600, 1600L, 1L);
  k_dense_sparse<7><<<T_BINS, 256, 0, stream>>>(s3b, WT1, zA, 1600, 300);
  k_fir<float, false><<<(300 * T_BINS) / 256, 256, 0, stream>>>(zA, pA, srm, 300);
  k_scan<unsigned char><<<2, 256, 0, stream>>>(pA, s4b, 300, 300L, 1L);
  k_dense_sparse<2><<<T_BINS, 256, 0, stream>>>(s4b, WT2, zA, 300, 150);
  k_fir<float, false><<<(150 * T_BINS) / 256, 256, 0, stream>>>(zA, pA, srm, 150);
  k_scan<unsigned char><<<1, 256, 0, stream>>>(pA, s5b, 150, 150L, 1L);
  k_dense_sparse<1><<<T_BINS, 256, 0, stream>>>(s5b, WT3, zA, 150, 10);
  k_fir<float, false><<<(10 * T_BINS) / 256, 256, 0, stream>>>(zA, pA, srm, 10);
  k_scan<float><<<1, 64, 0, stream>>>(pA, out, 10, 1L, 2048L);

  (void)in_sizes; (void)n_in; (void)out_size; (void)ws_size;
}